// Round 2
// baseline (110619.812 us; speedup 1.0000x reference)
//
#include <hip/hip_runtime.h>
#include <hip/hip_cooperative_groups.h>
#include <stdint.h>

namespace cg = cooperative_groups;

#define B_ 64
#define T_ 512
#define D_ 512
#define U_ 1024
#define TC 32           // timesteps per chunk
#define NCHUNK (T_ / TC)

typedef unsigned short u16;
typedef u16 ushort8  __attribute__((ext_vector_type(8)));
typedef __bf16 bf16x8 __attribute__((ext_vector_type(8)));
typedef float f32x4  __attribute__((ext_vector_type(4)));

static __device__ __forceinline__ u16 f2bf(float f) {
  unsigned u = __builtin_bit_cast(unsigned, f);
  u += 0x7FFFu + ((u >> 16) & 1u);      // round-to-nearest-even
  return (u16)(u >> 16);
}
static __device__ __forceinline__ float bf2f(u16 h) {
  unsigned u = ((unsigned)h) << 16;
  return __builtin_bit_cast(float, u);
}

// ---------------- prep: pack weights [K][4096] f32 -> [n'][K] bf16, n' = (u<<2)|g ----------------

__global__ __launch_bounds__(256) void pack_wt(const float* __restrict__ src,
                                               u16* __restrict__ dst, int K) {
  __shared__ float tile[32][33];
  int n0 = blockIdx.x * 32, k0 = blockIdx.y * 32;
  int tx = threadIdx.x, ty = threadIdx.y;  // 32 x 8
#pragma unroll
  for (int r = 0; r < 4; ++r) {
    int k = k0 + ty + r * 8;
    tile[ty + r * 8][tx] = src[(long)k * 4096 + n0 + tx];
  }
  __syncthreads();
#pragma unroll
  for (int r = 0; r < 4; ++r) {
    int n = n0 + ty + r * 8;
    int np = ((n & 1023) << 2) | (n >> 10);
    dst[(long)np * K + k0 + tx] = f2bf(tile[tx][ty + r * 8]);
  }
}

__global__ __launch_bounds__(256) void pack_bias(const float* __restrict__ b1,
                                                 const float* __restrict__ b2,
                                                 float* __restrict__ bp) {
  int n = blockIdx.x * 256 + threadIdx.x;  // 0..4095
  int np = ((n & 1023) << 2) | (n >> 10);
  bp[np] = b1[n];
  bp[4096 + np] = b2[n];
}

// ---------------- zx GEMM: zx[b*TC+tt][n'] = A[b, t0+tt, :] @ Wp[n',:]^T + bias[n'] ----------------
// A rows have length K (layer1: x f32 K=512; layer2: h1ln bf16 K=1024), T_-row batch stride.
// tile 128x128, BK=64, 512 threads (8 waves, 2x4), acc 4x2 frags of 16x16.

template <bool AF32>
__global__ __launch_bounds__(512) void zx_gemm(const void* __restrict__ Av, int t0, int K,
                                               const u16* __restrict__ Bp,
                                               const float* __restrict__ biasp,
                                               float* __restrict__ zxo) {
  __shared__ __align__(16) u16 Als[128][72];
  __shared__ __align__(16) u16 Bls[128][72];
  const int tid = threadIdx.x;
  const int mt = blockIdx.x, nt = blockIdx.y;
  const int l = tid & 63, w = tid >> 6;
  const int wm = w >> 2, wn = w & 3;            // wave tile: 64 rows x 32 cols
  const int sr = tid >> 2, skq = (tid & 3) * 16;  // staging: row, k-offset (16 elems)

  const int gr = mt * 128 + sr;                 // global M row = b*TC + tt
  const int b = gr >> 5, tt = gr & 31;
  const long abase = ((long)b * T_ + t0 + tt) * K;
  const float* Af = (const float*)Av;
  const u16* Ah = (const u16*)Av;

  const int nc = K >> 6;
  float4 raf[4];
  ushort8 rah[2];
  ushort8 rb[2];

  auto gload = [&](int ch) {
    long k0 = (long)ch << 6;
    if constexpr (AF32) {
#pragma unroll
      for (int i = 0; i < 4; ++i)
        raf[i] = *reinterpret_cast<const float4*>(Af + abase + k0 + skq + i * 4);
    } else {
#pragma unroll
      for (int i = 0; i < 2; ++i)
        rah[i] = *reinterpret_cast<const ushort8*>(Ah + abase + k0 + skq + i * 8);
    }
#pragma unroll
    for (int i = 0; i < 2; ++i)
      rb[i] = *reinterpret_cast<const ushort8*>(Bp + (long)(nt * 128 + sr) * K + k0 + skq + i * 8);
  };

  f32x4 acc[4][2];
#pragma unroll
  for (int fm = 0; fm < 4; ++fm)
#pragma unroll
    for (int fn = 0; fn < 2; ++fn) acc[fm][fn] = (f32x4){0.f, 0.f, 0.f, 0.f};

  gload(0);
  for (int ch = 0; ch < nc; ++ch) {
    __syncthreads();
    if constexpr (AF32) {
      const float* pr = (const float*)raf;
      ushort8 lo, hi;
#pragma unroll
      for (int j = 0; j < 8; ++j) { lo[j] = f2bf(pr[j]); hi[j] = f2bf(pr[8 + j]); }
      *reinterpret_cast<ushort8*>(&Als[sr][skq]) = lo;
      *reinterpret_cast<ushort8*>(&Als[sr][skq + 8]) = hi;
    } else {
      *reinterpret_cast<ushort8*>(&Als[sr][skq]) = rah[0];
      *reinterpret_cast<ushort8*>(&Als[sr][skq + 8]) = rah[1];
    }
    *reinterpret_cast<ushort8*>(&Bls[sr][skq]) = rb[0];
    *reinterpret_cast<ushort8*>(&Bls[sr][skq + 8]) = rb[1];
    __syncthreads();
    if (ch + 1 < nc) gload(ch + 1);
#pragma unroll
    for (int ks = 0; ks < 2; ++ks) {
#pragma unroll
      for (int fm = 0; fm < 4; ++fm) {
        bf16x8 a = __builtin_bit_cast(bf16x8,
            *reinterpret_cast<const ushort8*>(&Als[wm * 64 + fm * 16 + (l & 15)][ks * 32 + (l >> 4) * 8]));
#pragma unroll
        for (int fn = 0; fn < 2; ++fn) {
          bf16x8 bb = __builtin_bit_cast(bf16x8,
              *reinterpret_cast<const ushort8*>(&Bls[wn * 32 + fn * 16 + (l & 15)][ks * 32 + (l >> 4) * 8]));
          acc[fm][fn] = __builtin_amdgcn_mfma_f32_16x16x32_bf16(a, bb, acc[fm][fn], 0, 0, 0);
        }
      }
    }
  }

  // epilogue: D row=(l>>4)*4+j, col=l&15
#pragma unroll
  for (int fm = 0; fm < 4; ++fm)
#pragma unroll
    for (int fn = 0; fn < 2; ++fn) {
      int col = nt * 128 + wn * 32 + fn * 16 + (l & 15);
      float bv = biasp[col];
#pragma unroll
      for (int j = 0; j < 4; ++j) {
        int row = mt * 128 + wm * 64 + fm * 16 + (l >> 4) * 4 + j;
        zxo[(long)row * 4096 + col] = acc[fm][fn][j] + bv;
      }
    }
}

// ---------------- persistent LSTM chunk (cooperative) ----------------
// grid 256 = (mh: 2 batch-halves) x (cg: 128 col-groups of 8 units*4 gates).
// LDS: [0,64K) h-half staging (32 rows x 2048B, XOR-swizzled); [64K,128K) R-slice (32 n'-cols).
// Pls (4KB) and Zls (4KB) alias the h region between barriers.

__global__ __launch_bounds__(512) void lstm_chunk(const float* __restrict__ zx,
                                                  const u16* __restrict__ Rp,
                                                  float* __restrict__ cst,
                                                  u16* __restrict__ hA, u16* __restrict__ hB,
                                                  u16* __restrict__ hseq, int t0) {
  __shared__ __align__(16) unsigned char smem[131072];
  u16* const hbuf = (u16*)smem;
  u16* const rbuf = (u16*)(smem + 65536);
  float* const Pls = (float*)smem;            // 4 slots x 64 lanes x 16B
  float* const Zls = (float*)(smem + 4096);   // [32][32] f32

  cg::grid_group grid = cg::this_grid();

  const int tid = threadIdx.x;
  const int bid = blockIdx.x;
  const int mh = bid & 1;          // batch half: rows mh*32..+31
  const int cgp = bid >> 1;        // 0..127: units u0=cgp*8, n'0 = cgp*32
  const int n0 = cgp * 32;
  const int l = tid & 63, w = tid >> 6;
  const int mf = w & 1, nf = (w >> 1) & 1, kh = w >> 2;

  // ---- load R slice into LDS once (swizzled) ----
#pragma unroll
  for (int it = 0; it < 8; ++it) {
    int d = (it * 512 + tid) * 16;          // byte in 64KB
    int row = d >> 11;                      // n' local 0..31
    int kb = d & 2047;
    ushort8 v = *reinterpret_cast<const ushort8*>(Rp + (((long)(n0 + row)) << 10) + (kb >> 1));
    *reinterpret_cast<ushort8*>((unsigned char*)rbuf + row * 2048 + (kb ^ ((row & 7) << 4))) = v;
  }

  // ---- per-thread gate-phase state ----
  const int gr_ = tid >> 3, guu = tid & 7;            // r 0..31, unit 0..7 (threads 0..255)
  const int gb = mh * 32 + gr_;
  const int gu = cgp * 8 + guu;
  const long cidx = (long)gb * U_ + gu;
  float creg = 0.f;
  if (tid < 256) creg = cst[cidx];

  // frag read constants
  const int arow = mf * 16 + (l & 15);
  const int bcol = nf * 16 + (l & 15);
  const unsigned aswz = (unsigned)((arow & 7) << 4);
  const unsigned bswz = (unsigned)((bcol & 7) << 4);
  const unsigned kbase = (unsigned)(kh * 1024 + ((l >> 4) << 4));  // byte offset
  const unsigned char* const abase_p = (const unsigned char*)hbuf + arow * 2048;
  const unsigned char* const bbase_p = (const unsigned char*)rbuf + bcol * 2048;

  __syncthreads();

  for (int tt = 0; tt < TC; ++tt) {
    const u16* hr = (tt & 1) ? hB : hA;
    u16* hw = (tt & 1) ? hA : hB;

    // ---- stage h-half (rows mh*32..+31), linear global read, swizzled LDS write ----
#pragma unroll
    for (int it = 0; it < 8; ++it) {
      int d = (it * 512 + tid) * 16;
      int row = d >> 11;
      int kb = d & 2047;
      ushort8 v = *reinterpret_cast<const ushort8*>(hr + (((long)(mh * 32 + row)) << 10) + (kb >> 1));
      *reinterpret_cast<ushort8*>((unsigned char*)hbuf + row * 2048 + (kb ^ ((row & 7) << 4))) = v;
    }
    __syncthreads();

    // ---- MFMA: wave (mf,nf,kh): 16 K-steps over K-half ----
    f32x4 acc = {0.f, 0.f, 0.f, 0.f};
#pragma unroll
    for (int ks = 0; ks < 16; ++ks) {
      unsigned kb = kbase + ks * 64;
      bf16x8 a = __builtin_bit_cast(bf16x8,
          *reinterpret_cast<const ushort8*>(abase_p + (kb ^ aswz)));
      bf16x8 bb = __builtin_bit_cast(bf16x8,
          *reinterpret_cast<const ushort8*>(bbase_p + (kb ^ bswz)));
      acc = __builtin_amdgcn_mfma_f32_16x16x32_bf16(a, bb, acc, 0, 0, 0);
    }
    __syncthreads();   // all LDS reads done; scratch aliasing safe

    if (kh == 1) *reinterpret_cast<f32x4*>(Pls + ((w - 4) * 64 + l) * 4) = acc;
    __syncthreads();
    if (kh == 0) {
      f32x4 p = *reinterpret_cast<const f32x4*>(Pls + (w * 64 + l) * 4);
      f32x4 z = acc + p;
#pragma unroll
      for (int j = 0; j < 4; ++j)
        Zls[(mf * 16 + (l >> 4) * 4 + j) * 32 + nf * 16 + (l & 15)] = z[j];
    }
    __syncthreads();

    // ---- gates + state (threads 0..255: one (b,u) each) ----
    if (tid < 256) {
      f32x4 zr = *reinterpret_cast<const f32x4*>(Zls + gr_ * 32 + guu * 4);
      f32x4 zv = *reinterpret_cast<const f32x4*>(zx + ((long)gb * TC + tt) * 4096 + (long)gu * 4);
      float zi = zr[0] + zv[0], zf = zr[1] + zv[1], zg = zr[2] + zv[2], zo = zr[3] + zv[3];
      float ig = 1.f / (1.f + expf(-zi));
      float fg = 1.f / (1.f + expf(-zf));
      float og = 1.f / (1.f + expf(-zo));
      creg = fg * creg + ig * zg;
      u16 hv = f2bf(og * creg);
      hw[(long)gb * U_ + gu] = hv;
      if (hseq) hseq[((long)gb * T_ + t0 + tt) * U_ + gu] = hv;
    }

    if (tt + 1 < TC) {
      __threadfence();
      grid.sync();
      __threadfence();
    }
  }

  if (tid < 256) cst[cidx] = creg;
}

// ---------------- LayerNorm + tanh ----------------

__global__ __launch_bounds__(256) void ln_tanh_seq(u16* __restrict__ h1seq,
                                                   const float* __restrict__ gamma,
                                                   const float* __restrict__ beta) {
  __shared__ float sbuf[8];
  u16* row = h1seq + (long)blockIdx.x * U_;
  float x[4];
#pragma unroll
  for (int j = 0; j < 4; ++j) x[j] = bf2f(row[threadIdx.x + 256 * j]);
  float s = x[0] + x[1] + x[2] + x[3];
  for (int o = 32; o > 0; o >>= 1) s += __shfl_down(s, o, 64);
  if ((threadIdx.x & 63) == 0) sbuf[threadIdx.x >> 6] = s;
  __syncthreads();
  float mu = (sbuf[0] + sbuf[1] + sbuf[2] + sbuf[3]) * (1.f / 1024.f);
  float d[4], s2 = 0.f;
#pragma unroll
  for (int j = 0; j < 4; ++j) { d[j] = x[j] - mu; s2 += d[j] * d[j]; }
  for (int o = 32; o > 0; o >>= 1) s2 += __shfl_down(s2, o, 64);
  if ((threadIdx.x & 63) == 0) sbuf[4 + (threadIdx.x >> 6)] = s2;
  __syncthreads();
  float inv = rsqrtf((sbuf[4] + sbuf[5] + sbuf[6] + sbuf[7]) * (1.f / 1024.f) + 1e-3f);
#pragma unroll
  for (int j = 0; j < 4; ++j) {
    int u = threadIdx.x + 256 * j;
    row[u] = f2bf(tanhf(d[j] * inv * gamma[u] + beta[u]));
  }
}

__global__ __launch_bounds__(256) void ln_tanh_final(const u16* __restrict__ h2,
                                                     const float* __restrict__ gamma,
                                                     const float* __restrict__ beta,
                                                     float* __restrict__ out) {
  __shared__ float sbuf[8];
  const u16* row = h2 + (long)blockIdx.x * U_;
  float x[4];
#pragma unroll
  for (int j = 0; j < 4; ++j) x[j] = bf2f(row[threadIdx.x + 256 * j]);
  float s = x[0] + x[1] + x[2] + x[3];
  for (int o = 32; o > 0; o >>= 1) s += __shfl_down(s, o, 64);
  if ((threadIdx.x & 63) == 0) sbuf[threadIdx.x >> 6] = s;
  __syncthreads();
  float mu = (sbuf[0] + sbuf[1] + sbuf[2] + sbuf[3]) * (1.f / 1024.f);
  float d[4], s2 = 0.f;
#pragma unroll
  for (int j = 0; j < 4; ++j) { d[j] = x[j] - mu; s2 += d[j] * d[j]; }
  for (int o = 32; o > 0; o >>= 1) s2 += __shfl_down(s2, o, 64);
  if ((threadIdx.x & 63) == 0) sbuf[4 + (threadIdx.x >> 6)] = s2;
  __syncthreads();
  float inv = rsqrtf((sbuf[4] + sbuf[5] + sbuf[6] + sbuf[7]) * (1.f / 1024.f) + 1e-3f);
#pragma unroll
  for (int j = 0; j < 4; ++j) {
    int u = threadIdx.x + 256 * j;
    out[(long)blockIdx.x * U_ + u] = tanhf(d[j] * inv * gamma[u] + beta[u]);
  }
}

// ---------------- launcher ----------------

extern "C" void kernel_launch(void* const* d_in, const int* in_sizes, int n_in,
                              void* d_out, int out_size, void* d_ws, size_t ws_size,
                              hipStream_t stream) {
  const float* x      = (const float*)d_in[0];
  const float* W1     = (const float*)d_in[1];
  const float* R1     = (const float*)d_in[2];
  const float* b1     = (const float*)d_in[3];
  const float* gamma1 = (const float*)d_in[4];
  const float* beta1  = (const float*)d_in[5];
  const float* W2     = (const float*)d_in[6];
  const float* R2     = (const float*)d_in[7];
  const float* b2     = (const float*)d_in[8];
  const float* gamma2 = (const float*)d_in[9];
  const float* beta2  = (const float*)d_in[10];
  float* out = (float*)d_out;

  char* base = (char*)d_ws;
  size_t off = 0;
  auto alloc = [&](size_t bytes) -> void* {
    void* p = base + off;
    off += (bytes + 255) & ~(size_t)255;
    return p;
  };
  u16*   Wp1   = (u16*)alloc((size_t)4096 * D_ * 2);           // 4 MB
  u16*   Rp1   = (u16*)alloc((size_t)4096 * U_ * 2);           // 8 MB
  u16*   Wp2   = (u16*)alloc((size_t)4096 * U_ * 2);           // 8 MB
  u16*   Rp2   = (u16*)alloc((size_t)4096 * U_ * 2);           // 8 MB
  float* biasp = (float*)alloc((size_t)2 * 4096 * 4);          // 32 KB
  float* zx    = (float*)alloc((size_t)B_ * TC * 4096 * 4);    // 33.5 MB
  u16*   h1seq = (u16*)alloc((size_t)B_ * T_ * U_ * 2);        // 67 MB
  float* c1    = (float*)alloc((size_t)B_ * U_ * 4);
  float* c2    = (float*)alloc((size_t)B_ * U_ * 4);
  u16*   h1a   = (u16*)alloc((size_t)B_ * U_ * 2);
  u16*   h1b   = (u16*)alloc((size_t)B_ * U_ * 2);
  u16*   h2a   = (u16*)alloc((size_t)B_ * U_ * 2);
  u16*   h2b   = (u16*)alloc((size_t)B_ * U_ * 2);

  // prep
  pack_wt<<<dim3(128, 16), dim3(32, 8), 0, stream>>>(W1, Wp1, D_);
  pack_wt<<<dim3(128, 32), dim3(32, 8), 0, stream>>>(R1, Rp1, U_);
  pack_wt<<<dim3(128, 32), dim3(32, 8), 0, stream>>>(W2, Wp2, U_);
  pack_wt<<<dim3(128, 32), dim3(32, 8), 0, stream>>>(R2, Rp2, U_);
  pack_bias<<<16, 256, 0, stream>>>(b1, b2, biasp);
  hipMemsetAsync(c1, 0, (size_t)B_ * U_ * 4, stream);
  hipMemsetAsync(c2, 0, (size_t)B_ * U_ * 4, stream);
  hipMemsetAsync(h1a, 0, (size_t)B_ * U_ * 2, stream);
  hipMemsetAsync(h1b, 0, (size_t)B_ * U_ * 2, stream);
  hipMemsetAsync(h2a, 0, (size_t)B_ * U_ * 2, stream);
  hipMemsetAsync(h2b, 0, (size_t)B_ * U_ * 2, stream);

  // layer 1
  for (int c = 0; c < NCHUNK; ++c) {
    int t0 = c * TC;
    zx_gemm<true><<<dim3(16, 32), 512, 0, stream>>>((const void*)x, t0, D_, Wp1, biasp, zx);
    const float* p_zx = zx; const u16* p_R = Rp1; float* p_c = c1;
    u16* p_hA = h1a; u16* p_hB = h1b; u16* p_hs = h1seq; int p_t0 = t0;
    void* args[7] = {&p_zx, &p_R, &p_c, &p_hA, &p_hB, &p_hs, &p_t0};
    hipLaunchCooperativeKernel((void*)lstm_chunk, dim3(256), dim3(512), args, 0, stream);
  }
  ln_tanh_seq<<<B_ * T_, 256, 0, stream>>>(h1seq, gamma1, beta1);

  // layer 2
  for (int c = 0; c < NCHUNK; ++c) {
    int t0 = c * TC;
    zx_gemm<false><<<dim3(16, 32), 512, 0, stream>>>((const void*)h1seq, t0, U_, Wp2, biasp + 4096, zx);
    const float* p_zx = zx; const u16* p_R = Rp2; float* p_c = c2;
    u16* p_hA = h2a; u16* p_hB = h2b; u16* p_hs = nullptr; int p_t0 = t0;
    void* args[7] = {&p_zx, &p_R, &p_c, &p_hA, &p_hB, &p_hs, &p_t0};
    hipLaunchCooperativeKernel((void*)lstm_chunk, dim3(256), dim3(512), args, 0, stream);
  }
  ln_tanh_final<<<B_, 256, 0, stream>>>(h2a, gamma2, beta2, out);
}

// Round 3
// 5370.295 us; speedup vs baseline: 20.5985x; 20.5985x over previous
//
#include <hip/hip_runtime.h>
#include <stdint.h>

#define B_ 64
#define T_ 512
#define D_ 512
#define U_ 1024
#define TC 32
#define NCH 16   // chunks per layer

typedef unsigned short u16;
typedef u16 ushort8  __attribute__((ext_vector_type(8)));
typedef __bf16 bf16x8 __attribute__((ext_vector_type(8)));
typedef float f32x4  __attribute__((ext_vector_type(4)));

static __device__ __forceinline__ u16 f2bf(float f) {
  unsigned u = __builtin_bit_cast(unsigned, f);
  u += 0x7FFFu + ((u >> 16) & 1u);      // round-to-nearest-even
  return (u16)(u >> 16);
}
static __device__ __forceinline__ float bf2f(u16 h) {
  unsigned u = ((unsigned)h) << 16;
  return __builtin_bit_cast(float, u);
}

// ---------------- prep: pack weights [K][4096] f32 -> [n'][K] bf16, n' = (u<<2)|g ----------------

__global__ __launch_bounds__(256) void pack_wt(const float* __restrict__ src,
                                               u16* __restrict__ dst, int K) {
  __shared__ float tile[32][33];
  int n0 = blockIdx.x * 32, k0 = blockIdx.y * 32;
  int tx = threadIdx.x, ty = threadIdx.y;  // 32 x 8
#pragma unroll
  for (int r = 0; r < 4; ++r) {
    int k = k0 + ty + r * 8;
    tile[ty + r * 8][tx] = src[(long)k * 4096 + n0 + tx];
  }
  __syncthreads();
#pragma unroll
  for (int r = 0; r < 4; ++r) {
    int n = n0 + ty + r * 8;
    int np = ((n & 1023) << 2) | (n >> 10);
    dst[(long)np * K + k0 + tx] = f2bf(tile[tx][ty + r * 8]);
  }
}

__global__ __launch_bounds__(256) void pack_bias(const float* __restrict__ b1,
                                                 const float* __restrict__ b2,
                                                 float* __restrict__ bp) {
  int n = blockIdx.x * 256 + threadIdx.x;  // 0..4095
  int np = ((n & 1023) << 2) | (n >> 10);
  bp[np] = b1[n];
  bp[4096 + np] = b2[n];
}

// ---------------- zx GEMM: zx[b*TC+tt][n'] = A[row] @ Wp[n',:]^T + bias[n'] ----------------
// A row base = b*sB + tt*sT (elements); layer1: A=x f32 (pointer pre-offset by t0), K=512;
// layer2: A=h1ln bf16, K=1024. tile 128x128, BK=64, 512 threads, acc 4x2 frags.

template <bool AF32>
__global__ __launch_bounds__(512) void zx_gemm(const void* __restrict__ Av, long sB, long sT,
                                               int K, const u16* __restrict__ Bp,
                                               const float* __restrict__ biasp,
                                               float* __restrict__ zxo) {
  __shared__ __align__(16) u16 Als[128][72];
  __shared__ __align__(16) u16 Bls[128][72];
  const int tid = threadIdx.x;
  const int mt = blockIdx.x, nt = blockIdx.y;
  const int l = tid & 63, w = tid >> 6;
  const int wm = w >> 2, wn = w & 3;              // wave tile: 64 rows x 32 cols
  const int sr = tid >> 2, skq = (tid & 3) * 16;  // staging: row, k-offset (16 elems)

  const int gr = mt * 128 + sr;                   // global M row = b*TC + tt
  const int b = gr >> 5, tt = gr & 31;
  const long abase = (long)b * sB + (long)tt * sT;
  const float* Af = (const float*)Av;
  const u16* Ah = (const u16*)Av;

  const int nc = K >> 6;
  float4 raf[4];
  ushort8 rah[2];
  ushort8 rb[2];

  auto gload = [&](int ch) {
    long k0 = (long)ch << 6;
    if constexpr (AF32) {
#pragma unroll
      for (int i = 0; i < 4; ++i)
        raf[i] = *reinterpret_cast<const float4*>(Af + abase + k0 + skq + i * 4);
    } else {
#pragma unroll
      for (int i = 0; i < 2; ++i)
        rah[i] = *reinterpret_cast<const ushort8*>(Ah + abase + k0 + skq + i * 8);
    }
#pragma unroll
    for (int i = 0; i < 2; ++i)
      rb[i] = *reinterpret_cast<const ushort8*>(Bp + (long)(nt * 128 + sr) * K + k0 + skq + i * 8);
  };

  f32x4 acc[4][2];
#pragma unroll
  for (int fm = 0; fm < 4; ++fm)
#pragma unroll
    for (int fn = 0; fn < 2; ++fn) acc[fm][fn] = (f32x4){0.f, 0.f, 0.f, 0.f};

  gload(0);
  for (int ch = 0; ch < nc; ++ch) {
    __syncthreads();
    if constexpr (AF32) {
      const float* pr = (const float*)raf;
      ushort8 lo, hi;
#pragma unroll
      for (int j = 0; j < 8; ++j) { lo[j] = f2bf(pr[j]); hi[j] = f2bf(pr[8 + j]); }
      *reinterpret_cast<ushort8*>(&Als[sr][skq]) = lo;
      *reinterpret_cast<ushort8*>(&Als[sr][skq + 8]) = hi;
    } else {
      *reinterpret_cast<ushort8*>(&Als[sr][skq]) = rah[0];
      *reinterpret_cast<ushort8*>(&Als[sr][skq + 8]) = rah[1];
    }
    *reinterpret_cast<ushort8*>(&Bls[sr][skq]) = rb[0];
    *reinterpret_cast<ushort8*>(&Bls[sr][skq + 8]) = rb[1];
    __syncthreads();
    if (ch + 1 < nc) gload(ch + 1);
#pragma unroll
    for (int ks = 0; ks < 2; ++ks) {
#pragma unroll
      for (int fm = 0; fm < 4; ++fm) {
        bf16x8 a = __builtin_bit_cast(bf16x8,
            *reinterpret_cast<const ushort8*>(&Als[wm * 64 + fm * 16 + (l & 15)][ks * 32 + (l >> 4) * 8]));
#pragma unroll
        for (int fn = 0; fn < 2; ++fn) {
          bf16x8 bb = __builtin_bit_cast(bf16x8,
              *reinterpret_cast<const ushort8*>(&Bls[wn * 32 + fn * 16 + (l & 15)][ks * 32 + (l >> 4) * 8]));
          acc[fm][fn] = __builtin_amdgcn_mfma_f32_16x16x32_bf16(a, bb, acc[fm][fn], 0, 0, 0);
        }
      }
    }
  }

  // epilogue: D row=(l>>4)*4+j, col=l&15
#pragma unroll
  for (int fm = 0; fm < 4; ++fm)
#pragma unroll
    for (int fn = 0; fn < 2; ++fn) {
      int col = nt * 128 + wn * 32 + fn * 16 + (l & 15);
      float bv = biasp[col];
#pragma unroll
      for (int j = 0; j < 4; ++j) {
        int row = mt * 128 + wm * 64 + fm * 16 + (l >> 4) * 4 + j;
        zxo[(long)row * 4096 + col] = acc[fm][fn][j] + bv;
      }
    }
}

// ---------------- dual-layer LSTM step ----------------
// grid 256: blocks 0..127 = layer1 (chunk p, step tt), 128..255 = layer2 (chunk p-1, step tt).
// Per block: z-tile = all 64 batch rows x 32 gate-cols, K=1024 (h @ R). 512 thr = 8 waves,
// wave w: rows (w>>1)*16, cols (w&1)*16. BK=128, reg-prefetch, padded LDS.

__global__ __launch_bounds__(512) void step2(
    const float* __restrict__ zx1, const u16* __restrict__ R1p, float* __restrict__ c1v,
    const u16* __restrict__ h1r, u16* __restrict__ h1w, u16* __restrict__ h1s,
    const float* __restrict__ zx2, const u16* __restrict__ R2p, float* __restrict__ c2v,
    const u16* __restrict__ h2r, u16* __restrict__ h2w,
    int tt, int act1, int act2) {
  const int layer = blockIdx.x >> 7;
  if (layer ? (!act2) : (!act1)) return;

  __shared__ __align__(16) u16 Als[64][136];   // h tile, +8 pad (2-way bank alias = free)
  __shared__ __align__(16) u16 Bls[32][136];   // R tile
  __shared__ float Zls[64][36];

  const float* zx = layer ? zx2 : zx1;
  const u16* Rp   = layer ? R2p : R1p;
  float* cv       = layer ? c2v : c1v;
  const u16* hr   = layer ? h2r : h1r;
  u16* hw         = layer ? h2w : h1w;

  const int cb = blockIdx.x & 127;
  const int n0 = cb * 32;
  const int tid = threadIdx.x;
  const int l = tid & 63, w = tid >> 6;
  const int wm = w >> 1, wn = w & 1;

  const int arow = tid >> 3, ak = (tid & 7) * 16;   // A: 64 rows x 128k, 16 elems/thread
  const int brow = tid >> 4, bk = (tid & 15) * 8;   // B: 32 rows x 128k, 8 elems/thread

  ushort8 ra0, ra1, rbv;
  auto gload = [&](int ch) {
    const int k0 = ch << 7;
    ra0 = *reinterpret_cast<const ushort8*>(hr + arow * U_ + k0 + ak);
    ra1 = *reinterpret_cast<const ushort8*>(hr + arow * U_ + k0 + ak + 8);
    rbv = *reinterpret_cast<const ushort8*>(Rp + (long)(n0 + brow) * U_ + k0 + bk);
  };

  f32x4 acc = {0.f, 0.f, 0.f, 0.f};
  gload(0);
  for (int ch = 0; ch < 8; ++ch) {
    __syncthreads();
    *reinterpret_cast<ushort8*>(&Als[arow][ak]) = ra0;
    *reinterpret_cast<ushort8*>(&Als[arow][ak + 8]) = ra1;
    *reinterpret_cast<ushort8*>(&Bls[brow][bk]) = rbv;
    __syncthreads();
    if (ch < 7) gload(ch + 1);
#pragma unroll
    for (int ks = 0; ks < 4; ++ks) {
      bf16x8 a = __builtin_bit_cast(bf16x8,
          *reinterpret_cast<const ushort8*>(&Als[wm * 16 + (l & 15)][ks * 32 + (l >> 4) * 8]));
      bf16x8 bb = __builtin_bit_cast(bf16x8,
          *reinterpret_cast<const ushort8*>(&Bls[wn * 16 + (l & 15)][ks * 32 + (l >> 4) * 8]));
      acc = __builtin_amdgcn_mfma_f32_16x16x32_bf16(a, bb, acc, 0, 0, 0);
    }
  }

  // acc -> Zls: D row=(l>>4)*4+j, col=l&15
  {
    int r0 = (l >> 4) * 4, col = wn * 16 + (l & 15);
#pragma unroll
    for (int j = 0; j < 4; ++j) Zls[wm * 16 + r0 + j][col] = acc[j];
  }
  __syncthreads();

  // gates: one (b,u) per thread
  {
    int b = tid >> 3, uu = tid & 7;
    int u = cb * 8 + uu;
    float z0 = Zls[b][uu * 4], z1 = Zls[b][uu * 4 + 1];
    float z2 = Zls[b][uu * 4 + 2], z3 = Zls[b][uu * 4 + 3];
    f32x4 zv = *reinterpret_cast<const f32x4*>(zx + ((long)b * TC + tt) * 4096 + n0 + uu * 4);
    float zi = z0 + zv[0], zf = z1 + zv[1], zg = z2 + zv[2], zo = z3 + zv[3];
    float ig = 1.f / (1.f + expf(-zi));
    float fg = 1.f / (1.f + expf(-zf));
    float og = 1.f / (1.f + expf(-zo));
    long ci = (long)b * U_ + u;
    float cn = fg * cv[ci] + ig * zg;
    cv[ci] = cn;
    u16 hv = f2bf(og * cn);
    hw[ci] = hv;
    if (layer == 0) h1s[(long)b * ((long)T_ * U_) + u] = hv;
  }
}

// ---------------- LayerNorm + tanh ----------------

// chunk LN: h1seq rows (b, t0+tt) -> h1ln[(b*TC+tt)][u] = tanh(LN(h))
__global__ __launch_bounds__(256) void ln_chunk(const u16* __restrict__ h1seq, int t0,
                                                const float* __restrict__ gamma,
                                                const float* __restrict__ beta,
                                                u16* __restrict__ dst) {
  __shared__ float sbuf[8];
  int row = blockIdx.x;            // 0..2047
  int b = row >> 5, tt = row & 31;
  const u16* src = h1seq + ((long)b * T_ + t0 + tt) * U_;
  u16* drow = dst + (long)row * U_;
  float x[4];
#pragma unroll
  for (int j = 0; j < 4; ++j) x[j] = bf2f(src[threadIdx.x + 256 * j]);
  float s = x[0] + x[1] + x[2] + x[3];
  for (int o = 32; o > 0; o >>= 1) s += __shfl_down(s, o, 64);
  if ((threadIdx.x & 63) == 0) sbuf[threadIdx.x >> 6] = s;
  __syncthreads();
  float mu = (sbuf[0] + sbuf[1] + sbuf[2] + sbuf[3]) * (1.f / 1024.f);
  float d[4], s2 = 0.f;
#pragma unroll
  for (int j = 0; j < 4; ++j) { d[j] = x[j] - mu; s2 += d[j] * d[j]; }
  for (int o = 32; o > 0; o >>= 1) s2 += __shfl_down(s2, o, 64);
  if ((threadIdx.x & 63) == 0) sbuf[4 + (threadIdx.x >> 6)] = s2;
  __syncthreads();
  float inv = rsqrtf((sbuf[4] + sbuf[5] + sbuf[6] + sbuf[7]) * (1.f / 1024.f) + 1e-3f);
#pragma unroll
  for (int j = 0; j < 4; ++j) {
    int u = threadIdx.x + 256 * j;
    drow[u] = f2bf(tanhf(d[j] * inv * gamma[u] + beta[u]));
  }
}

__global__ __launch_bounds__(256) void ln_tanh_final(const u16* __restrict__ h2,
                                                     const float* __restrict__ gamma,
                                                     const float* __restrict__ beta,
                                                     float* __restrict__ out) {
  __shared__ float sbuf[8];
  const u16* row = h2 + (long)blockIdx.x * U_;
  float x[4];
#pragma unroll
  for (int j = 0; j < 4; ++j) x[j] = bf2f(row[threadIdx.x + 256 * j]);
  float s = x[0] + x[1] + x[2] + x[3];
  for (int o = 32; o > 0; o >>= 1) s += __shfl_down(s, o, 64);
  if ((threadIdx.x & 63) == 0) sbuf[threadIdx.x >> 6] = s;
  __syncthreads();
  float mu = (sbuf[0] + sbuf[1] + sbuf[2] + sbuf[3]) * (1.f / 1024.f);
  float d[4], s2 = 0.f;
#pragma unroll
  for (int j = 0; j < 4; ++j) { d[j] = x[j] - mu; s2 += d[j] * d[j]; }
  for (int o = 32; o > 0; o >>= 1) s2 += __shfl_down(s2, o, 64);
  if ((threadIdx.x & 63) == 0) sbuf[4 + (threadIdx.x >> 6)] = s2;
  __syncthreads();
  float inv = rsqrtf((sbuf[4] + sbuf[5] + sbuf[6] + sbuf[7]) * (1.f / 1024.f) + 1e-3f);
#pragma unroll
  for (int j = 0; j < 4; ++j) {
    int u = threadIdx.x + 256 * j;
    out[(long)blockIdx.x * U_ + u] = tanhf(d[j] * inv * gamma[u] + beta[u]);
  }
}

// ---------------- launcher ----------------

extern "C" void kernel_launch(void* const* d_in, const int* in_sizes, int n_in,
                              void* d_out, int out_size, void* d_ws, size_t ws_size,
                              hipStream_t stream) {
  const float* x      = (const float*)d_in[0];
  const float* W1     = (const float*)d_in[1];
  const float* R1     = (const float*)d_in[2];
  const float* b1     = (const float*)d_in[3];
  const float* gamma1 = (const float*)d_in[4];
  const float* beta1  = (const float*)d_in[5];
  const float* W2     = (const float*)d_in[6];
  const float* R2     = (const float*)d_in[7];
  const float* b2     = (const float*)d_in[8];
  const float* gamma2 = (const float*)d_in[9];
  const float* beta2  = (const float*)d_in[10];
  float* out = (float*)d_out;

  char* base = (char*)d_ws;
  size_t off = 0;
  auto alloc = [&](size_t bytes) -> void* {
    void* p = base + off;
    off += (bytes + 255) & ~(size_t)255;
    return p;
  };
  u16*   Wp1   = (u16*)alloc((size_t)4096 * D_ * 2);           // 4 MB
  u16*   Rp1   = (u16*)alloc((size_t)4096 * U_ * 2);           // 8 MB
  u16*   Wp2   = (u16*)alloc((size_t)4096 * U_ * 2);           // 8 MB
  u16*   Rp2   = (u16*)alloc((size_t)4096 * U_ * 2);           // 8 MB
  float* biasp = (float*)alloc((size_t)2 * 4096 * 4);          // 32 KB
  float* zxA   = (float*)alloc((size_t)B_ * TC * 4096 * 4);    // 33.5 MB (layer1 chunk)
  float* zxB   = (float*)alloc((size_t)B_ * TC * 4096 * 4);    // 33.5 MB (layer2 chunk)
  u16*   h1seq = (u16*)alloc((size_t)B_ * T_ * U_ * 2);        // 67 MB (raw h1)
  u16*   h1ln  = (u16*)alloc((size_t)B_ * TC * U_ * 2);        // 4.2 MB (tanh(LN(h1)) chunk)
  float* c1    = (float*)alloc((size_t)B_ * U_ * 4);
  float* c2    = (float*)alloc((size_t)B_ * U_ * 4);
  u16*   h1a   = (u16*)alloc((size_t)B_ * U_ * 2);
  u16*   h1b   = (u16*)alloc((size_t)B_ * U_ * 2);
  u16*   h2a   = (u16*)alloc((size_t)B_ * U_ * 2);
  u16*   h2b   = (u16*)alloc((size_t)B_ * U_ * 2);

  // prep
  pack_wt<<<dim3(128, 16), dim3(32, 8), 0, stream>>>(W1, Wp1, D_);
  pack_wt<<<dim3(128, 32), dim3(32, 8), 0, stream>>>(R1, Rp1, U_);
  pack_wt<<<dim3(128, 32), dim3(32, 8), 0, stream>>>(W2, Wp2, U_);
  pack_wt<<<dim3(128, 32), dim3(32, 8), 0, stream>>>(R2, Rp2, U_);
  pack_bias<<<16, 256, 0, stream>>>(b1, b2, biasp);
  hipMemsetAsync(c1, 0, (size_t)B_ * U_ * 4, stream);
  hipMemsetAsync(c2, 0, (size_t)B_ * U_ * 4, stream);
  hipMemsetAsync(h1a, 0, (size_t)B_ * U_ * 2, stream);
  hipMemsetAsync(h2a, 0, (size_t)B_ * U_ * 2, stream);

  // pipelined phases: phase p runs layer1 chunk p and layer2 chunk p-1
  for (int p = 0; p <= NCH; ++p) {
    int act1 = (p < NCH), act2 = (p >= 1);
    if (act1)
      zx_gemm<true><<<dim3(16, 32), 512, 0, stream>>>(
          (const void*)(x + (long)p * TC * D_), (long)T_ * D_, (long)D_, D_, Wp1, biasp, zxA);
    if (act2) {
      ln_chunk<<<B_ * TC, 256, 0, stream>>>(h1seq, (p - 1) * TC, gamma1, beta1, h1ln);
      zx_gemm<false><<<dim3(16, 32), 512, 0, stream>>>(
          (const void*)h1ln, (long)TC * U_, (long)U_, U_, Wp2, biasp + 4096, zxB);
    }
    for (int tt = 0; tt < TC; ++tt) {
      u16* h1r = (tt & 1) ? h1b : h1a;
      u16* h1w = (tt & 1) ? h1a : h1b;
      u16* h2r = (tt & 1) ? h2b : h2a;
      u16* h2w = (tt & 1) ? h2a : h2b;
      step2<<<256, 512, 0, stream>>>(zxA, Rp1, c1, h1r, h1w,
                                     h1seq + (long)(p * TC + tt) * U_,
                                     zxB, Rp2, c2, h2r, h2w, tt, act1, act2);
    }
  }
  ln_tanh_final<<<B_, 256, 0, stream>>>(h2a, gamma2, beta2, out);
}